// Round 6
// baseline (394.554 us; speedup 1.0000x reference)
//
#include <hip/hip_runtime.h>
#include <stdint.h>
#include <stddef.h>

// Problem constants (AttentiveTransformer: B=65536, D_IN=128, F=512, fp32)
#define NROWS 65536
#define DK 128
#define NF 512
#define BN_EPS 1e-3f

typedef __attribute__((ext_vector_type(8))) short short8;   // 8 x bf16 (4 VGPR)
typedef __attribute__((ext_vector_type(4))) float f32x4;    // MFMA acc / vec4

__device__ __forceinline__ unsigned short f2bf(float f) {
  unsigned int u = __builtin_bit_cast(unsigned int, f);
  u += 0x7fffu + ((u >> 16) & 1u);     // round-to-nearest-even
  return (unsigned short)(u >> 16);
}
__device__ __forceinline__ float bf2f(unsigned short h) {
  unsigned int u = ((unsigned int)h) << 16;
  return __builtin_bit_cast(float, u);
}

// ---------------------------------------------------------------------------
// Prep: blocks 0..255 transpose W [128][512] -> Wt hi/lo bf16 [512][128],
//       with BN scale alpha = gamma*rsqrt(var+eps) BAKED INTO the columns
//       (z = inp.W' + delta). Block 256 computes delta.
// ---------------------------------------------------------------------------
__global__ void prep_kernel(const float* __restrict__ W,
                            const float* __restrict__ bias,
                            const float* __restrict__ gamma,
                            const float* __restrict__ beta,
                            const float* __restrict__ mean,
                            const float* __restrict__ var,
                            unsigned short* __restrict__ wt_hi,
                            unsigned short* __restrict__ wt_lo,
                            float* __restrict__ delta) {
  int bid = blockIdx.x;
  int tid = threadIdx.x;
  if (bid < 256) {
    int idx = bid * 256 + tid;        // 0..65535 over [128][512]
    int d = idx >> 9;                 // k index 0..127
    int f = idx & 511;                // col index 0..511
    float a = gamma[f] * rsqrtf(var[f] + BN_EPS);
    float w = W[idx] * a;             // fold BN scale into the weight column
    unsigned short wh = f2bf(w);
    float rem = w - bf2f(wh);
    wt_hi[(size_t)f * DK + d] = wh;
    wt_lo[(size_t)f * DK + d] = f2bf(rem);
  } else {
#pragma unroll
    for (int i = 0; i < 2; ++i) {
      int f = tid + i * 256;
      float a = gamma[f] * rsqrtf(var[f] + BN_EPS);
      delta[f] = (bias[f] - mean[f]) * a + beta[f];
    }
  }
}

// ---------------------------------------------------------------------------
// Fused, barrier-free, OPERAND-SWAPPED MFMA.
// Each wave owns 16 batch rows and computes ALL 512 features with
//   D = mfma(Wt_frag /*A operand*/, inp_frag /*B operand*/, acc)
// so D[feature][batch]: lane l holds features t*16 + q*4 + {0..3} of batch
// row li (q = l>>4, li = l&15). The fragment LOADS are identical to the
// classic orientation (both operands are [row][k] row-major) — only the
// intrinsic argument order changes. This gives:
//   * float4-aligned prior/delta/out access per lane (no scalar gather)
//   * sparsemax reduction over just 4 lanes (shfl_xor 16, 32 — 2 steps)
//   * acc IS z end-to-end: no LDS, no __syncthreads, no redistribution
// Register budget: acc[32] f32x4 = 128 + A-frags 32 + temps ≈ ~200 VGPR.
// __launch_bounds__(256) with NO min-wave cap: 2 waves/SIMD, no spill
// (round-2's spill came from the (256,2) 128-reg cap; round-4's from
// (256,4)). Waves are independent -> phase drift across the 8 resident
// waves/CU overlaps MFMA, Michelot VALU chains, and HBM streams (m114).
// Wt is streamed in full per wave (256 KB, L2-resident per XCD).
// ---------------------------------------------------------------------------
__global__ __launch_bounds__(256) void fused_kernel(
    const float* __restrict__ inp,            // [65536][128]
    const float* __restrict__ prior,          // [65536][512]
    const unsigned short* __restrict__ wt_hi, // [512][128] bf16 hi (alpha-baked)
    const unsigned short* __restrict__ wt_lo, // [512][128] bf16 lo
    const float* __restrict__ delta,          // [512]
    float* __restrict__ out) {                // [65536][512]
  const int tid = threadIdx.x;
  const int w = tid >> 6;        // wave 0..3
  const int l = tid & 63;        // lane
  const int q = l >> 4;          // quad 0..3  (feature sub-chunk)
  const int li = l & 15;         // batch row within wave
  const size_t row = (size_t)blockIdx.x * 64 + w * 16 + li;  // this lane's row

  // ---- B-operand (inp row) load + split-convert to bf16 hi/lo ----
  const float* arow = inp + row * DK + q * 8;
  short8 ah[4], al[4];
#pragma unroll
  for (int kk = 0; kk < 4; ++kk) {
    float4 v0 = *(const float4*)(arow + kk * 32);
    float4 v1 = *(const float4*)(arow + kk * 32 + 4);
    float av[8] = {v0.x, v0.y, v0.z, v0.w, v1.x, v1.y, v1.z, v1.w};
    short8 h, lo;
#pragma unroll
    for (int j = 0; j < 8; ++j) {
      unsigned short hb = f2bf(av[j]);
      h[j] = (short)hb;
      lo[j] = (short)f2bf(av[j] - bf2f(hb));
    }
    ah[kk] = h;
    al[kk] = lo;
  }

  // ---- MFMA: 32 feature-tiles, 3-product split (W=wh+wl, x=ah+al):
  //      W.x ~= wh.ah + wl.ah + wh.al  (wl.al dropped, 2nd order) ----
  f32x4 acc[32];
#pragma unroll
  for (int t = 0; t < 32; ++t) acc[t] = (f32x4){0.f, 0.f, 0.f, 0.f};

#pragma unroll
  for (int t = 0; t < 32; ++t) {
    const unsigned short* wbh = wt_hi + (size_t)(t * 16 + li) * DK + q * 8;
    const unsigned short* wbl = wt_lo + (size_t)(t * 16 + li) * DK + q * 8;
#pragma unroll
    for (int kk = 0; kk < 4; ++kk) {
      short8 wh = *(const short8*)(wbh + kk * 32);
      short8 wl = *(const short8*)(wbl + kk * 32);
      // Wt fragment as the A operand, inp fragment as B -> D[feature][batch]
      acc[t] = __builtin_amdgcn_mfma_f32_16x16x32_bf16(wh, ah[kk], acc[t], 0, 0, 0);
      acc[t] = __builtin_amdgcn_mfma_f32_16x16x32_bf16(wl, ah[kk], acc[t], 0, 0, 0);
      acc[t] = __builtin_amdgcn_mfma_f32_16x16x32_bf16(wh, al[kk], acc[t], 0, 0, 0);
    }
  }

  // ---- BN + prior, in place: z = (acc + delta) * prior (float4 per lane) --
  const float* prow = prior + row * NF + q * 4;
  const float* drow = delta + q * 4;
#pragma unroll
  for (int t = 0; t < 32; ++t) {
    f32x4 pv = *(const f32x4*)(prow + t * 16);
    f32x4 dv = *(const f32x4*)(drow + t * 16);
#pragma unroll
    for (int r = 0; r < 4; ++r) acc[t][r] = (acc[t][r] + dv[r]) * pv[r];
  }

  // ---- row max: 128 local elems, then reduce over the 4 q-lanes ----
  float mx4[4];
#pragma unroll
  for (int r = 0; r < 4; ++r) mx4[r] = acc[0][r];
#pragma unroll
  for (int t = 1; t < 32; ++t)
#pragma unroll
    for (int r = 0; r < 4; ++r) mx4[r] = fmaxf(mx4[r], acc[t][r]);
  float mx = fmaxf(fmaxf(mx4[0], mx4[1]), fmaxf(mx4[2], mx4[3]));
  mx = fmaxf(mx, __shfl_xor(mx, 16, 64));
  mx = fmaxf(mx, __shfl_xor(mx, 32, 64));

  // ---- Michelot fixed-point: tau <- (sum_S - 1)/|S|, S = {z > tau} ----
  float tau = mx - 1.0f;
  float cprev = -1.0f;
  for (int it = 0; it < 40; ++it) {
    float s = 0.0f, c = 0.0f;
#pragma unroll
    for (int t = 0; t < 32; ++t) {
#pragma unroll
      for (int r = 0; r < 4; ++r) {
        bool in = acc[t][r] > tau;
        s += in ? acc[t][r] : 0.0f;
        c += in ? 1.0f : 0.0f;
      }
    }
    s += __shfl_xor(s, 16, 64);
    c += __shfl_xor(c, 16, 64);
    s += __shfl_xor(s, 32, 64);
    c += __shfl_xor(c, 32, 64);
    tau = (s - 1.0f) / c;
    if (__all(c == cprev)) break;   // support fixed -> converged (idempotent)
    cprev = c;
  }

  // ---- output: float4 per lane, same pattern as prior ----
  float* orow = out + row * NF + q * 4;
#pragma unroll
  for (int t = 0; t < 32; ++t) {
    f32x4 ov;
#pragma unroll
    for (int r = 0; r < 4; ++r) ov[r] = fmaxf(acc[t][r] - tau, 0.0f);
    *(f32x4*)(orow + t * 16) = ov;
  }
}

// ---------------------------------------------------------------------------
extern "C" void kernel_launch(void* const* d_in, const int* in_sizes, int n_in,
                              void* d_out, int out_size, void* d_ws, size_t ws_size,
                              hipStream_t stream) {
  const float* inp   = (const float*)d_in[0];   // [65536][128]
  const float* prior = (const float*)d_in[1];   // [65536][512]
  const float* W     = (const float*)d_in[2];   // [128][512]
  const float* bias  = (const float*)d_in[3];   // [512]
  const float* gamma = (const float*)d_in[4];
  const float* beta  = (const float*)d_in[5];
  const float* mean  = (const float*)d_in[6];
  const float* var   = (const float*)d_in[7];
  float* out = (float*)d_out;

  // workspace carve: 131072 + 131072 + 2048 bytes
  unsigned short* wt_hi = (unsigned short*)d_ws;
  unsigned short* wt_lo = wt_hi + (size_t)NF * DK;
  float* delta = (float*)(wt_lo + (size_t)NF * DK);

  prep_kernel<<<257, 256, 0, stream>>>(W, bias, gamma, beta, mean, var,
                                       wt_hi, wt_lo, delta);
  fused_kernel<<<NROWS / 64, 256, 0, stream>>>(inp, prior, wt_hi, wt_lo,
                                               delta, out);
}

// Round 8
// 332.171 us; speedup vs baseline: 1.1878x; 1.1878x over previous
//
#include <hip/hip_runtime.h>
#include <stdint.h>
#include <stddef.h>

// Problem constants (AttentiveTransformer: B=65536, D_IN=128, F=512, fp32)
#define NROWS 65536
#define DK 128
#define NF 512
#define BN_EPS 1e-3f

typedef __attribute__((ext_vector_type(8))) short short8;   // 8 x bf16 (4 VGPR)
typedef __attribute__((ext_vector_type(4))) float f32x4;    // MFMA acc / vec4

__device__ __forceinline__ unsigned short f2bf(float f) {
  unsigned int u = __builtin_bit_cast(unsigned int, f);
  u += 0x7fffu + ((u >> 16) & 1u);     // round-to-nearest-even
  return (unsigned short)(u >> 16);
}
__device__ __forceinline__ float bf2f(unsigned short h) {
  unsigned int u = ((unsigned int)h) << 16;
  return __builtin_bit_cast(float, u);
}

// ---------------------------------------------------------------------------
// Prep: blocks 0..255 transpose W [128][512] -> Wt hi/lo bf16 [512][128],
//       with BN scale alpha = gamma*rsqrt(var+eps) BAKED INTO the columns
//       (z = inp.W' + delta). Block 256 computes delta.
// ---------------------------------------------------------------------------
__global__ void prep_kernel(const float* __restrict__ W,
                            const float* __restrict__ bias,
                            const float* __restrict__ gamma,
                            const float* __restrict__ beta,
                            const float* __restrict__ mean,
                            const float* __restrict__ var,
                            unsigned short* __restrict__ wt_hi,
                            unsigned short* __restrict__ wt_lo,
                            float* __restrict__ delta) {
  int bid = blockIdx.x;
  int tid = threadIdx.x;
  if (bid < 256) {
    int idx = bid * 256 + tid;        // 0..65535 over [128][512]
    int d = idx >> 9;                 // k index 0..127
    int f = idx & 511;                // col index 0..511
    float a = gamma[f] * rsqrtf(var[f] + BN_EPS);
    float w = W[idx] * a;             // fold BN scale into the weight column
    unsigned short wh = f2bf(w);
    float rem = w - bf2f(wh);
    wt_hi[(size_t)f * DK + d] = wh;
    wt_lo[(size_t)f * DK + d] = f2bf(rem);
  } else {
#pragma unroll
    for (int i = 0; i < 2; ++i) {
      int f = tid + i * 256;
      float a = gamma[f] * rsqrtf(var[f] + BN_EPS);
      delta[f] = (bias[f] - mean[f]) * a + beta[f];
    }
  }
}

// ---------------------------------------------------------------------------
// Kernel A: GEMM (split-bf16, operand-swapped MFMA) + BN, streaming z to
// global (the OUT buffer doubles as z scratch; kernel B overwrites it).
// Wave = 32 batch rows x all 512 features. Operand swap (Wt as the A
// operand) gives D[feature][batch]: lane l holds features t*16+q*4+{0..3}
// of batch row rg*16+li -> float4 z stores, fully coalesced (64B/row
// sector). acc lives PER-TILE only (compute t -> BN -> store -> next t):
// 2 live acc tiles instead of 32 -> ~110 VGPR, no spill, 4 waves/SIMD.
// Single-phase: nothing downstream, waves just stream. 6 MFMAs per
// wh/wl load pair (2 row-groups x 3 products) = round-0's L2 intensity.
// ---------------------------------------------------------------------------
__global__ __launch_bounds__(256, 4) void gemm_bn_kernel(
    const float* __restrict__ inp,            // [65536][128]
    const unsigned short* __restrict__ wt_hi, // [512][128] bf16 hi (alpha-baked)
    const unsigned short* __restrict__ wt_lo, // [512][128] bf16 lo
    const float* __restrict__ delta,          // [512]
    float* __restrict__ zout) {               // [65536][512] (= out buffer)
  const int tid = threadIdx.x;
  const int w = tid >> 6;        // wave 0..3
  const int l = tid & 63;        // lane
  const int q = l >> 4;          // quad 0..3 (feature sub-chunk / k-chunk)
  const int li = l & 15;         // row-in-group / feature-row of Wt frag
  const size_t r0 = (size_t)blockIdx.x * 128 + w * 32;   // wave's 32 rows

  // ---- load + split-convert the 32 input rows (B operand fragments) ----
  short8 ah[2][4], al[2][4];
#pragma unroll
  for (int rg = 0; rg < 2; ++rg) {
    const float* arow = inp + (r0 + rg * 16 + li) * DK + q * 8;
#pragma unroll
    for (int kk = 0; kk < 4; ++kk) {
      float4 v0 = *(const float4*)(arow + kk * 32);
      float4 v1 = *(const float4*)(arow + kk * 32 + 4);
      float av[8] = {v0.x, v0.y, v0.z, v0.w, v1.x, v1.y, v1.z, v1.w};
      short8 h, lo;
#pragma unroll
      for (int j = 0; j < 8; ++j) {
        unsigned short hb = f2bf(av[j]);
        h[j] = (short)hb;
        lo[j] = (short)f2bf(av[j] - bf2f(hb));
      }
      ah[rg][kk] = h;
      al[rg][kk] = lo;
    }
  }

  // ---- stream feature tiles: MFMA (3-product split) -> BN -> store ----
  float* zrow0 = zout + (r0 + li) * NF;        // rg=0 store base
  float* zrow1 = zout + (r0 + 16 + li) * NF;   // rg=1 store base
#pragma unroll 2
  for (int t = 0; t < 32; ++t) {
    const unsigned short* wbh = wt_hi + (size_t)(t * 16 + li) * DK + q * 8;
    const unsigned short* wbl = wt_lo + (size_t)(t * 16 + li) * DK + q * 8;
    f32x4 acc0 = (f32x4){0.f, 0.f, 0.f, 0.f};
    f32x4 acc1 = (f32x4){0.f, 0.f, 0.f, 0.f};
#pragma unroll
    for (int kk = 0; kk < 4; ++kk) {
      short8 wh = *(const short8*)(wbh + kk * 32);
      short8 wl = *(const short8*)(wbl + kk * 32);
      acc0 = __builtin_amdgcn_mfma_f32_16x16x32_bf16(wh, ah[0][kk], acc0, 0, 0, 0);
      acc1 = __builtin_amdgcn_mfma_f32_16x16x32_bf16(wh, ah[1][kk], acc1, 0, 0, 0);
      acc0 = __builtin_amdgcn_mfma_f32_16x16x32_bf16(wl, ah[0][kk], acc0, 0, 0, 0);
      acc1 = __builtin_amdgcn_mfma_f32_16x16x32_bf16(wl, ah[1][kk], acc1, 0, 0, 0);
      acc0 = __builtin_amdgcn_mfma_f32_16x16x32_bf16(wh, al[0][kk], acc0, 0, 0, 0);
      acc1 = __builtin_amdgcn_mfma_f32_16x16x32_bf16(wh, al[1][kk], acc1, 0, 0, 0);
    }
    f32x4 dv = *(const f32x4*)(delta + t * 16 + q * 4);
#pragma unroll
    for (int r = 0; r < 4; ++r) {
      acc0[r] += dv[r];
      acc1[r] += dv[r];
    }
    *(f32x4*)(zrow0 + t * 16 + q * 4) = acc0;
    *(f32x4*)(zrow1 + t * 16 + q * 4) = acc1;
  }
}

// ---------------------------------------------------------------------------
// Kernel B: per-row prior-scaled sparsemax, pure streaming. Reads z from
// OUT (written by kernel A; 128 MB -> largely L3-resident), multiplies by
// prior, Michelot projection, writes the mask back IN PLACE over out.
// Safe: each quad touches only its own row, values staged in registers
// (all reads complete before any store issues via data dependency).
// Quad (16 lanes) owns one row; ~60 VGPR, no LDS -> high waves/SIMD;
// 16384 independent waves of load -> short VALU chain -> store: TLP alone
// saturates bandwidth. Michelot loop hard-capped at 40 iterations.
// ---------------------------------------------------------------------------
__global__ __launch_bounds__(256, 4) void sparsemax_kernel(
    const float* __restrict__ prior,          // [65536][512]
    float* __restrict__ out) {                // in: z, out: mask
  const int tid = threadIdx.x;
  const int w = tid >> 6;        // wave 0..3
  const int l = tid & 63;        // lane
  const int q = l >> 4;          // quad 0..3
  const int li = l & 15;
  const size_t row = (size_t)blockIdx.x * 16 + w * 4 + q;

  const float* zr = out + row * NF + li * 4;
  const float* pr = prior + row * NF + li * 4;

  float z[32];
#pragma unroll
  for (int j = 0; j < 8; ++j) {
    f32x4 zv = *(const f32x4*)(zr + 64 * j);
    f32x4 pv = *(const f32x4*)(pr + 64 * j);
    z[4 * j + 0] = zv[0] * pv[0];
    z[4 * j + 1] = zv[1] * pv[1];
    z[4 * j + 2] = zv[2] * pv[2];
    z[4 * j + 3] = zv[3] * pv[3];
  }

  // row max (reduce over the quad's 16 lanes: xor masks 1,2,4,8)
  float mx = z[0];
#pragma unroll
  for (int j = 1; j < 32; ++j) mx = fmaxf(mx, z[j]);
#pragma unroll
  for (int off = 1; off <= 8; off <<= 1) mx = fmaxf(mx, __shfl_xor(mx, off, 64));

  // Michelot fixed-point: tau <- (sum_S - 1)/|S|, S = {z > tau}
  float tau = mx - 1.0f;
  float cprev = -1.0f;
  for (int it = 0; it < 40; ++it) {
    float s = 0.0f, c = 0.0f;
#pragma unroll
    for (int j = 0; j < 32; ++j) {
      bool in = z[j] > tau;
      s += in ? z[j] : 0.0f;
      c += in ? 1.0f : 0.0f;
    }
#pragma unroll
    for (int off = 1; off <= 8; off <<= 1) {
      s += __shfl_xor(s, off, 64);
      c += __shfl_xor(c, off, 64);
    }
    tau = (s - 1.0f) / c;
    if (__all(c == cprev)) break;   // support fixed -> converged (idempotent)
    cprev = c;
  }

  float* orow = out + row * NF + li * 4;
#pragma unroll
  for (int j = 0; j < 8; ++j) {
    f32x4 ov;
    ov[0] = fmaxf(z[4 * j + 0] - tau, 0.0f);
    ov[1] = fmaxf(z[4 * j + 1] - tau, 0.0f);
    ov[2] = fmaxf(z[4 * j + 2] - tau, 0.0f);
    ov[3] = fmaxf(z[4 * j + 3] - tau, 0.0f);
    *(f32x4*)(orow + 64 * j) = ov;
  }
}

// ---------------------------------------------------------------------------
extern "C" void kernel_launch(void* const* d_in, const int* in_sizes, int n_in,
                              void* d_out, int out_size, void* d_ws, size_t ws_size,
                              hipStream_t stream) {
  const float* inp   = (const float*)d_in[0];   // [65536][128]
  const float* prior = (const float*)d_in[1];   // [65536][512]
  const float* W     = (const float*)d_in[2];   // [128][512]
  const float* bias  = (const float*)d_in[3];   // [512]
  const float* gamma = (const float*)d_in[4];
  const float* beta  = (const float*)d_in[5];
  const float* mean  = (const float*)d_in[6];
  const float* var   = (const float*)d_in[7];
  float* out = (float*)d_out;

  // workspace carve: 131072 + 131072 + 2048 bytes
  unsigned short* wt_hi = (unsigned short*)d_ws;
  unsigned short* wt_lo = wt_hi + (size_t)NF * DK;
  float* delta = (float*)(wt_lo + (size_t)NF * DK);

  prep_kernel<<<257, 256, 0, stream>>>(W, bias, gamma, beta, mean, var,
                                       wt_hi, wt_lo, delta);
  // A: z -> out (out doubles as the z scratch buffer)
  gemm_bn_kernel<<<NROWS / 128, 256, 0, stream>>>(inp, wt_hi, wt_lo, delta, out);
  // B: out <- sparsemax(out * prior), in place
  sparsemax_kernel<<<NROWS / 16, 256, 0, stream>>>(prior, out);
}